// Round 4
// baseline (281.375 us; speedup 1.0000x reference)
//
#include <hip/hip_runtime.h>
#include <math.h>

namespace {

typedef float f4 __attribute__((ext_vector_type(4)));

constexpr int NPTS = 256 * 128;            // 32768 points
constexpr int OUTS = 257;                  // D+1
constexpr size_t HOFF = (size_t)NPTS * OUTS;

constexpr int K1_PPW  = 16;                // points per wave (encode)
constexpr int K1_PPB  = 64;                // 4 waves per block
constexpr int K1_GRID = 4 * (NPTS / K1_PPB);  // channel-major: 2048 blocks

constexpr int K2_PPB  = 16;                // 4 waves x 4 groups
constexpr int K2_GRID = NPTS / K2_PPB;     // 2048 blocks

__device__ __forceinline__ float frcp(float x)   { return __builtin_amdgcn_rcpf(x); }
__device__ __forceinline__ float fsqrt_(float x) { return __builtin_amdgcn_sqrtf(x); }
// acosh(a) = log(a + sqrt(a^2-1)); fma keeps a^2-1 accurate near a=1
__device__ __forceinline__ float facosh(float a) {
  return __logf(a + fsqrt_(fmaf(a, a, -1.f)));
}
__device__ __forceinline__ void fsinhcosh(float x, float& sh, float& ch) {
  float e = __expf(x), ei = frcp(e);
  sh = 0.5f * (e - ei);
  ch = 0.5f * (e + ei);
}
__device__ __forceinline__ float fsinh(float x) {
  float e = __expf(x);
  return 0.5f * (e - frcp(e));
}
__device__ __forceinline__ float dot4(f4 a, f4 b) {
  return a.x * b.x + a.y * b.y + a.z * b.z + a.w * b.w;
}
__device__ __forceinline__ f4 fma4s(float a, f4 b, f4 c) {
  f4 av = {a, a, a, a};
  return __builtin_elementwise_fma(av, b, c);
}

// one butterfly step: x += rotate-within-row16(x, N) — pure VALU (v_add_f32+DPP)
template <int CTRL>
__device__ __forceinline__ float dpp_add(float x) {
  int t = __builtin_amdgcn_update_dpp(0, __builtin_bit_cast(int, x), CTRL, 0xf, 0xf, true);
  return x + __builtin_bit_cast(float, t);
}

// sum across each 16-lane row via DPP rotations (8,4,2,1)
template <int NB>
__device__ __forceinline__ void grp_reduce(float* v) {
#pragma unroll
  for (int i = 0; i < NB; ++i) {
    float t = v[i];
    t = dpp_add<0x128>(t);   // row_ror:8
    t = dpp_add<0x124>(t);   // row_ror:4
    t = dpp_add<0x122>(t);   // row_ror:2
    t = dpp_add<0x121>(t);   // row_ror:1
    v[i] = t;
  }
}

// full 64-lane sum: row16 reduce + cross-row (16,32)
template <int NB>
__device__ __forceinline__ void wave_reduce64(float* v) {
  grp_reduce<NB>(v);
#pragma unroll
  for (int i = 0; i < NB; ++i) {
    v[i] += __shfl_xor(v[i], 16, 64);
    v[i] += __shfl_xor(v[i], 32, 64);
  }
}

// ================= kernel 1: encode + to_hyperbolic =================
// One CHANNEL per block: W^T staged once, one barrier, then stream 64 points.
__global__ __launch_bounds__(256) void encode_kernel(
    const float* __restrict__ xt, const float* __restrict__ xc,
    const float* __restrict__ xf, const float* __restrict__ xr,
    const float* __restrict__ Wt, const float* __restrict__ bt,
    const float* __restrict__ Wc, const float* __restrict__ bc,
    const float* __restrict__ Wf, const float* __restrict__ bf,
    const float* __restrict__ Wr, const float* __restrict__ br,
    const float* __restrict__ esp, float* __restrict__ out) {
  // wlds[s*256 + d] = W[d][s]; write lanes-contiguous (free), read 1KB rows (free)
  __shared__ float wlds[32 * 256];

  const int tid  = threadIdx.x;
  const int lane = tid & 63;
  const int wv   = __builtin_amdgcn_readfirstlane(tid >> 6);
  const int bid  = blockIdx.x;
  const int c    = bid & 3;                      // channel
  const int pt0  = (bid >> 2) * K1_PPB + wv * K1_PPW;  // wave-uniform

  const float* xsarr[4] = {xt, xc, xf, xr};
  const float* Wsarr[4] = {Wt, Wc, Wf, Wr};
  const float* Bsarr[4] = {bt, bc, bf, br};

  // tanh(effective_scale) via native exp
  float es2 = __expf(2.f * esp[0]);
  const float ts = (es2 - 1.f) * frcp(es2 + 1.f);

  // ---- stage W_c transposed into LDS (thread tid owns W row d = tid) ----
  {
    const float* Wp = Wsarr[c];
    f4 wrow[8];
#pragma unroll
    for (int k = 0; k < 8; ++k) wrow[k] = *(const f4*)(Wp + tid * 32 + 4 * k);
#pragma unroll
    for (int k = 0; k < 8; ++k) {
      wlds[(4 * k + 0) * 256 + tid] = wrow[k].x;
      wlds[(4 * k + 1) * 256 + tid] = wrow[k].y;
      wlds[(4 * k + 2) * 256 + tid] = wrow[k].z;
      wlds[(4 * k + 3) * 256 + tid] = wrow[k].w;
    }
  }
  __syncthreads();                               // the only barrier

  // ---- encode 16 points: lane owns dims 4*lane..+3 of all 16 points ----
  f4 acc[K1_PPW];
  {
    f4 bv = ((const f4*)Bsarr[c])[lane];
#pragma unroll
    for (int p = 0; p < K1_PPW; ++p) acc[p] = bv;
  }
  const float* xp = xsarr[c] + (size_t)pt0 * 32; // wave-uniform -> s_load
#pragma unroll
  for (int s4 = 0; s4 < 8; ++s4) {
    f4 w4[4];
#pragma unroll
    for (int si = 0; si < 4; ++si)
      w4[si] = *(const f4*)&wlds[(4 * s4 + si) * 256 + 4 * lane];
#pragma unroll
    for (int p = 0; p < K1_PPW; ++p) {
      f4 xq = *(const f4*)(xp + 32 * p + 4 * s4);
      acc[p] = fma4s(xq.x, w4[0], acc[p]);
      acc[p] = fma4s(xq.y, w4[1], acc[p]);
      acc[p] = fma4s(xq.z, w4[2], acc[p]);
      acc[p] = fma4s(xq.w, w4[3], acc[p]);
    }
  }

  // ---- to_hyperbolic (64-lane layout; norms via full-wave reduce) ----
  float pa[K1_PPW];
#pragma unroll
  for (int p = 0; p < K1_PPW; ++p) {
    acc[p] = ts * acc[p];
    pa[p]  = dot4(acc[p], acc[p]);
  }
  wave_reduce64<K1_PPW>(pa);
#pragma unroll
  for (int p = 0; p < K1_PPW; ++p) {
    float n1  = fsqrt_(pa[p]);
    float n1m = fmaxf(n1, 1e-8f);
    float c1  = fminf(n1m, 1.5f) * frcp(n1m);    // clip-to-1.5 scale
    float n2  = c1 * n1;                         // norm after clip
    float nsx = fmaxf(n2, 1e-9f);
    float sh  = fsinh(n2);
    float rn  = frcp(nsx);
    float g   = sh * c1 * rn;
    float sxr = sh * n2 * rn;                    // ||xr||
    float xx0 = fsqrt_(fmaf(sxr, sxr, 1.f));     // projx
    f4 v = g * acc[p];
    float* o = out + (size_t)c * HOFF + (size_t)(pt0 + p) * OUTS;
    if (lane == 0) o[0] = xx0;
    int base = 1 + 4 * lane;
    o[base] = v.x; o[base + 1] = v.y; o[base + 2] = v.z; o[base + 3] = v.w;
  }
}

// ================= kernel 2: lorentz fusion =================
// No LDS, no barriers. Each 16-lane group owns one point; h re-read from out
// (L3-resident), which performs the 64-lane -> group-layout transpose for free.
__global__ __launch_bounds__(256) void fusion_kernel(
    const float* __restrict__ lwp, float* __restrict__ out) {
  const int tid  = threadIdx.x;
  const int lane = tid & 63;
  const int m    = lane & 15;              // lane within 16-lane group
  const int grp  = lane >> 4;              // group (= point) within wave
  const int wv   = tid >> 6;
  const int pt   = blockIdx.x * K2_PPB + wv * 4 + grp;

  // softmax of lorentz_weights
  float l0 = lwp[0], l1 = lwp[1], l2 = lwp[2], l3 = lwp[3];
  float mx = fmaxf(fmaxf(l0, l1), fmaxf(l2, l3));
  float e0 = __expf(l0 - mx), e1 = __expf(l1 - mx);
  float e2 = __expf(l2 - mx), e3 = __expf(l3 - mx);
  float ei = frcp(e0 + e1 + e2 + e3);
  const float wgt[4] = {e0 * ei, e1 * ei, e2 * ei, e3 * ei};

  // load h in group layout: lane owns dims 4m+64j..+3 of its point
  f4    h[4][4];
  float x0s[4];
  float r2s[4];
#pragma unroll
  for (int c = 0; c < 4; ++c) {
    const float* o = out + (size_t)c * HOFF + (size_t)pt * OUTS;
    x0s[c] = o[0];                         // broadcast load within group
#pragma unroll
    for (int j = 0; j < 4; ++j) h[c][j] = *(const f4*)&o[1 + 4 * m + 64 * j];
  }
  {
    float pa[4];
#pragma unroll
    for (int c = 0; c < 4; ++c) {
      float s = 0.f;
#pragma unroll
      for (int j = 0; j < 4; ++j) s += dot4(h[c][j], h[c][j]);
      pa[c] = s;
    }
    grp_reduce<4>(pa);
#pragma unroll
    for (int c = 0; c < 4; ++c) r2s[c] = pa[c];
  }

  float wt0 = 0.f;
  f4    wtr[4];
#pragma unroll
  for (int j = 0; j < 4; ++j) wtr[j] = (f4){0.f, 0.f, 0.f, 0.f};
#pragma unroll
  for (int c = 0; c < 4; ++c) {
    float y0    = x0s[c];
    float alpha = fmaxf(y0, 1.f + 1e-7f);
    float dist  = facosh(alpha);
    float u0    = y0 - alpha;
    float msq   = r2s[c] - u0 * u0;
    float un    = fsqrt_(fmaxf(msq, 1e-12f));
    float f     = wgt[c] * dist * frcp(un);
    wt0 = fmaf(f, u0, wt0);
#pragma unroll
    for (int j = 0; j < 4; ++j) wtr[j] = fma4s(f, h[c][j], wtr[j]);
  }
  float rrp = 0.f;
#pragma unroll
  for (int j = 0; j < 4; ++j) rrp += dot4(wtr[j], wtr[j]);
  grp_reduce<1>(&rrp);

  f4    mr[4];
  float mrr, m0;
  {
    float rr  = rrp;
    float nrm = fsqrt_(fmaf(wt0, wt0, rr));
    float scl = fminf(nrm, 2.f) * frcp(fmaxf(nrm, 1e-12f));
    float nr  = scl * fsqrt_(rr);                // spatial norm after clip
    float nsx = fmaxf(nr, 1e-9f);
    float g   = fsinh(nr) * scl * frcp(nsx);
#pragma unroll
    for (int j = 0; j < 4; ++j) mr[j] = g * wtr[j];
    mrr = g * g * rr;                            // ||mr||^2, algebraic
    m0  = fsqrt_(1.f + mrr);                     // projx
  }

#pragma unroll 1
  for (int it = 0; it < 5; ++it) {
    float dots[4];
#pragma unroll
    for (int c = 0; c < 4; ++c) {
      float d = 0.f;
#pragma unroll
      for (int j = 0; j < 4; ++j) d += dot4(mr[j], h[c][j]);
      dots[c] = d;
    }
    grp_reduce<4>(dots);

    float wv0 = 0.f;
    f4    wvr[4];
#pragma unroll
    for (int j = 0; j < 4; ++j) wvr[j] = (f4){0.f, 0.f, 0.f, 0.f};
#pragma unroll
    for (int c = 0; c < 4; ++c) {
      float d     = dots[c];
      float y0    = x0s[c];
      float ip    = fmaf(m0, y0, -d);            // -mink(mean, y)
      float alpha = fmaxf(ip, 1.f + 1e-7f);
      float dist  = facosh(alpha);
      float u0    = fmaf(-alpha, m0, y0);
      // ||ur||^2 = r2 - 2*alpha*dot + alpha^2*mrr (algebraic)
      float t   = fmaf(alpha, mrr, -2.f * d);
      float s2  = fmaf(alpha, t, r2s[c]);
      float msq = s2 - u0 * u0;
      float un  = fsqrt_(fmaxf(msq, 1e-12f));
      float f   = wgt[c] * dist * frcp(un);
      wv0 = fmaf(f, u0, wv0);
#pragma unroll
      for (int j = 0; j < 4; ++j) {
        f4 diff = fma4s(-alpha, mr[j], h[c][j]);
        wvr[j]  = fma4s(f, diff, wvr[j]);
      }
    }
    float pr[2] = {0.f, 0.f};
#pragma unroll
    for (int j = 0; j < 4; ++j) {
      pr[0] += dot4(wvr[j], wvr[j]);
      pr[1] += dot4(mr[j], wvr[j]);
    }
    grp_reduce<2>(pr);

    {
      float rr2  = pr[0];
      float mwv  = pr[1];
      float nrm2 = fsqrt_(fmaf(wv0, wv0, rr2));
      float sc2  = fminf(nrm2, 2.f) * frcp(fmaxf(nrm2, 1e-12f));
      float tt   = 0.1f * sc2;                   // fold clip + 0.1 step
      float msqu = tt * tt * (rr2 - wv0 * wv0);  // mink(u,u)
      float un2  = fsqrt_(fmaxf(msqu, 1e-12f));
      float shv, chv;
      fsinhcosh(un2, shv, chv);
      float gg = shv * tt * frcp(un2);
#pragma unroll
      for (int j = 0; j < 4; ++j) mr[j] = fma4s(chv, mr[j], gg * wvr[j]);
      // ||mr'||^2 = chv^2*mrr + 2*chv*gg*(mr.wvr) + gg^2*rr2 (algebraic)
      mrr = chv * chv * mrr + 2.f * chv * gg * mwv + gg * gg * rr2;
      m0  = fsqrt_(1.f + mrr);                   // projx
    }
  }

  {
    float* o = out + 4 * HOFF + (size_t)pt * OUTS;
    if (m == 0) o[0] = m0;
#pragma unroll
    for (int j = 0; j < 4; ++j) {
      int base = 1 + 4 * m + 64 * j;
      f4 v = mr[j];
      o[base] = v.x; o[base + 1] = v.y; o[base + 2] = v.z; o[base + 3] = v.w;
    }
  }
}

}  // namespace

extern "C" void kernel_launch(void* const* d_in, const int* in_sizes, int n_in,
                              void* d_out, int out_size, void* d_ws, size_t ws_size,
                              hipStream_t stream) {
  (void)in_sizes; (void)n_in; (void)out_size; (void)d_ws; (void)ws_size;
  encode_kernel<<<K1_GRID, 256, 0, stream>>>(
      (const float*)d_in[0], (const float*)d_in[1], (const float*)d_in[2],
      (const float*)d_in[3], (const float*)d_in[4], (const float*)d_in[5],
      (const float*)d_in[6], (const float*)d_in[7], (const float*)d_in[8],
      (const float*)d_in[9], (const float*)d_in[10], (const float*)d_in[11],
      (const float*)d_in[12], (float*)d_out);
  fusion_kernel<<<K2_GRID, 256, 0, stream>>>(
      (const float*)d_in[13], (float*)d_out);
}

// Round 5
// 272.911 us; speedup vs baseline: 1.0310x; 1.0310x over previous
//
#include <hip/hip_runtime.h>
#include <math.h>

namespace {

typedef float f4 __attribute__((ext_vector_type(4)));

constexpr int NPTS = 256 * 128;            // 32768 points
constexpr int OUTS = 257;                  // D+1
constexpr size_t HOFF = (size_t)NPTS * OUTS;

constexpr int K1_PPW  = 8;                 // points per wave (encode)
constexpr int K1_PPB  = 32;                // 4 waves per block
constexpr int K1_GRID = 4 * (NPTS / K1_PPB);  // channel-major: 4096 blocks

constexpr int K2_PPB  = 16;                // 4 waves x 4 groups
constexpr int K2_GRID = NPTS / K2_PPB;     // 2048 blocks

__device__ __forceinline__ float frcp(float x)   { return __builtin_amdgcn_rcpf(x); }
__device__ __forceinline__ float fsqrt_(float x) { return __builtin_amdgcn_sqrtf(x); }
// acosh(a) = log(a + sqrt(a^2-1)); fma keeps a^2-1 accurate near a=1
__device__ __forceinline__ float facosh(float a) {
  return __logf(a + fsqrt_(fmaf(a, a, -1.f)));
}
__device__ __forceinline__ void fsinhcosh(float x, float& sh, float& ch) {
  float e = __expf(x), ei = frcp(e);
  sh = 0.5f * (e - ei);
  ch = 0.5f * (e + ei);
}
__device__ __forceinline__ float fsinh(float x) {
  float e = __expf(x);
  return 0.5f * (e - frcp(e));
}
__device__ __forceinline__ float dot4(f4 a, f4 b) {
  return a.x * b.x + a.y * b.y + a.z * b.z + a.w * b.w;
}
__device__ __forceinline__ f4 fma4s(float a, f4 b, f4 c) {
  f4 av = {a, a, a, a};
  return __builtin_elementwise_fma(av, b, c);
}

// one butterfly step: x += rotate-within-row16(x, N) — pure VALU (v_add_f32+DPP)
template <int CTRL>
__device__ __forceinline__ float dpp_add(float x) {
  int t = __builtin_amdgcn_update_dpp(0, __builtin_bit_cast(int, x), CTRL, 0xf, 0xf, true);
  return x + __builtin_bit_cast(float, t);
}

// sum across each 16-lane row via DPP rotations (8,4,2,1)
template <int NB>
__device__ __forceinline__ void grp_reduce(float* v) {
#pragma unroll
  for (int i = 0; i < NB; ++i) {
    float t = v[i];
    t = dpp_add<0x128>(t);   // row_ror:8
    t = dpp_add<0x124>(t);   // row_ror:4
    t = dpp_add<0x122>(t);   // row_ror:2
    t = dpp_add<0x121>(t);   // row_ror:1
    v[i] = t;
  }
}

// full 64-lane sum: row16 reduce + cross-row (16,32)
template <int NB>
__device__ __forceinline__ void wave_reduce64(float* v) {
  grp_reduce<NB>(v);
#pragma unroll
  for (int i = 0; i < NB; ++i) {
    v[i] += __shfl_xor(v[i], 16, 64);
    v[i] += __shfl_xor(v[i], 32, 64);
  }
}

// ================= kernel 1: encode + to_hyperbolic =================
// One CHANNEL per block: W^T staged once, one barrier, stream 32 points/block.
// x is loaded via VMEM broadcast (laundered pointer) so it completes through
// vmcnt, independent of the ds_read lgkmcnt domain -> compiler can pipeline.
__global__ __launch_bounds__(256) void encode_kernel(
    const float* __restrict__ xt, const float* __restrict__ xc,
    const float* __restrict__ xf, const float* __restrict__ xr,
    const float* __restrict__ Wt, const float* __restrict__ bt,
    const float* __restrict__ Wc, const float* __restrict__ bc,
    const float* __restrict__ Wf, const float* __restrict__ bf,
    const float* __restrict__ Wr, const float* __restrict__ br,
    const float* __restrict__ esp, float* __restrict__ out) {
  // wlds[s*256 + d] = W[d][s]; write lanes-contiguous (free), read 1KB rows (free)
  __shared__ float wlds[32 * 256];

  const int tid  = threadIdx.x;
  const int lane = tid & 63;
  const int wv   = __builtin_amdgcn_readfirstlane(tid >> 6);
  const int bid  = blockIdx.x;
  const int c    = bid & 3;                      // channel
  const int pt0  = (bid >> 2) * K1_PPB + wv * K1_PPW;  // wave-uniform

  const float* xsarr[4] = {xt, xc, xf, xr};
  const float* Wsarr[4] = {Wt, Wc, Wf, Wr};
  const float* Bsarr[4] = {bt, bc, bf, br};

  // tanh(effective_scale) via native exp
  float es2 = __expf(2.f * esp[0]);
  const float ts = (es2 - 1.f) * frcp(es2 + 1.f);

  // ---- stage W_c transposed into LDS (thread tid owns W row d = tid) ----
  {
    const float* Wp = Wsarr[c];
    f4 wrow[8];
#pragma unroll
    for (int k = 0; k < 8; ++k) wrow[k] = *(const f4*)(Wp + tid * 32 + 4 * k);
#pragma unroll
    for (int k = 0; k < 8; ++k) {
      wlds[(4 * k + 0) * 256 + tid] = wrow[k].x;
      wlds[(4 * k + 1) * 256 + tid] = wrow[k].y;
      wlds[(4 * k + 2) * 256 + tid] = wrow[k].z;
      wlds[(4 * k + 3) * 256 + tid] = wrow[k].w;
    }
  }
  __syncthreads();                               // the only barrier

  // ---- encode 8 points: lane owns dims 4*lane..+3 of all 8 points ----
  f4 acc[K1_PPW];
  {
    f4 bv = ((const f4*)Bsarr[c])[lane];
#pragma unroll
    for (int p = 0; p < K1_PPW; ++p) acc[p] = bv;
  }
  // launder a zero through a VGPR so x loads take the VMEM (vmcnt) path
  // instead of s_load (lgkmcnt, which serializes against ds_read).
  int lz = 0;
  asm volatile("" : "+v"(lz));
  const float* xp = xsarr[c] + (size_t)pt0 * 32 + lz;
#pragma unroll
  for (int s4 = 0; s4 < 8; ++s4) {
    f4 w4[4];
#pragma unroll
    for (int si = 0; si < 4; ++si)
      w4[si] = *(const f4*)&wlds[(4 * s4 + si) * 256 + 4 * lane];
#pragma unroll
    for (int p = 0; p < K1_PPW; ++p) {
      f4 xq = *(const f4*)(xp + 32 * p + 4 * s4);   // VMEM broadcast, 1 txn
      acc[p] = fma4s(xq.x, w4[0], acc[p]);
      acc[p] = fma4s(xq.y, w4[1], acc[p]);
      acc[p] = fma4s(xq.z, w4[2], acc[p]);
      acc[p] = fma4s(xq.w, w4[3], acc[p]);
    }
  }

  // ---- to_hyperbolic (64-lane layout; norms via full-wave reduce) ----
  float pa[K1_PPW];
#pragma unroll
  for (int p = 0; p < K1_PPW; ++p) {
    acc[p] = ts * acc[p];
    pa[p]  = dot4(acc[p], acc[p]);
  }
  wave_reduce64<K1_PPW>(pa);
#pragma unroll
  for (int p = 0; p < K1_PPW; ++p) {
    float n1  = fsqrt_(pa[p]);
    float n1m = fmaxf(n1, 1e-8f);
    float c1  = fminf(n1m, 1.5f) * frcp(n1m);    // clip-to-1.5 scale
    float n2  = c1 * n1;                         // norm after clip
    float nsx = fmaxf(n2, 1e-9f);
    float sh  = fsinh(n2);
    float rn  = frcp(nsx);
    float g   = sh * c1 * rn;
    float sxr = sh * n2 * rn;                    // ||xr||
    float xx0 = fsqrt_(fmaf(sxr, sxr, 1.f));     // projx
    f4 v = g * acc[p];
    float* o = out + (size_t)c * HOFF + (size_t)(pt0 + p) * OUTS;
    if (lane == 0) o[0] = xx0;
    int base = 1 + 4 * lane;
    o[base] = v.x; o[base + 1] = v.y; o[base + 2] = v.z; o[base + 3] = v.w;
  }
}

// ================= kernel 2: lorentz fusion =================
// No LDS, no barriers. Each 16-lane group owns one point; h re-read from out
// (L3-resident), which performs the 64-lane -> group-layout transpose for free.
__global__ __launch_bounds__(256) void fusion_kernel(
    const float* __restrict__ lwp, float* __restrict__ out) {
  const int tid  = threadIdx.x;
  const int lane = tid & 63;
  const int m    = lane & 15;              // lane within 16-lane group
  const int grp  = lane >> 4;              // group (= point) within wave
  const int wv   = tid >> 6;
  const int pt   = blockIdx.x * K2_PPB + wv * 4 + grp;

  // softmax of lorentz_weights
  float l0 = lwp[0], l1 = lwp[1], l2 = lwp[2], l3 = lwp[3];
  float mx = fmaxf(fmaxf(l0, l1), fmaxf(l2, l3));
  float e0 = __expf(l0 - mx), e1 = __expf(l1 - mx);
  float e2 = __expf(l2 - mx), e3 = __expf(l3 - mx);
  float ei = frcp(e0 + e1 + e2 + e3);
  const float wgt[4] = {e0 * ei, e1 * ei, e2 * ei, e3 * ei};

  // load h in group layout: lane owns dims 4m+64j..+3 of its point
  f4    h[4][4];
  float x0s[4];
  float r2s[4];
#pragma unroll
  for (int c = 0; c < 4; ++c) {
    const float* o = out + (size_t)c * HOFF + (size_t)pt * OUTS;
    x0s[c] = o[0];                         // broadcast load within group
#pragma unroll
    for (int j = 0; j < 4; ++j) h[c][j] = *(const f4*)&o[1 + 4 * m + 64 * j];
  }
  {
    float pa[4];
#pragma unroll
    for (int c = 0; c < 4; ++c) {
      float s = 0.f;
#pragma unroll
      for (int j = 0; j < 4; ++j) s += dot4(h[c][j], h[c][j]);
      pa[c] = s;
    }
    grp_reduce<4>(pa);
#pragma unroll
    for (int c = 0; c < 4; ++c) r2s[c] = pa[c];
  }

  float wt0 = 0.f;
  f4    wtr[4];
#pragma unroll
  for (int j = 0; j < 4; ++j) wtr[j] = (f4){0.f, 0.f, 0.f, 0.f};
#pragma unroll
  for (int c = 0; c < 4; ++c) {
    float y0    = x0s[c];
    float alpha = fmaxf(y0, 1.f + 1e-7f);
    float dist  = facosh(alpha);
    float u0    = y0 - alpha;
    float msq   = r2s[c] - u0 * u0;
    float un    = fsqrt_(fmaxf(msq, 1e-12f));
    float f     = wgt[c] * dist * frcp(un);
    wt0 = fmaf(f, u0, wt0);
#pragma unroll
    for (int j = 0; j < 4; ++j) wtr[j] = fma4s(f, h[c][j], wtr[j]);
  }
  float rrp = 0.f;
#pragma unroll
  for (int j = 0; j < 4; ++j) rrp += dot4(wtr[j], wtr[j]);
  grp_reduce<1>(&rrp);

  f4    mr[4];
  float mrr, m0;
  {
    float rr  = rrp;
    float nrm = fsqrt_(fmaf(wt0, wt0, rr));
    float scl = fminf(nrm, 2.f) * frcp(fmaxf(nrm, 1e-12f));
    float nr  = scl * fsqrt_(rr);                // spatial norm after clip
    float nsx = fmaxf(nr, 1e-9f);
    float g   = fsinh(nr) * scl * frcp(nsx);
#pragma unroll
    for (int j = 0; j < 4; ++j) mr[j] = g * wtr[j];
    mrr = g * g * rr;                            // ||mr||^2, algebraic
    m0  = fsqrt_(1.f + mrr);                     // projx
  }

#pragma unroll 1
  for (int it = 0; it < 5; ++it) {
    float dots[4];
#pragma unroll
    for (int c = 0; c < 4; ++c) {
      float d = 0.f;
#pragma unroll
      for (int j = 0; j < 4; ++j) d += dot4(mr[j], h[c][j]);
      dots[c] = d;
    }
    grp_reduce<4>(dots);

    float wv0 = 0.f;
    f4    wvr[4];
#pragma unroll
    for (int j = 0; j < 4; ++j) wvr[j] = (f4){0.f, 0.f, 0.f, 0.f};
#pragma unroll
    for (int c = 0; c < 4; ++c) {
      float d     = dots[c];
      float y0    = x0s[c];
      float ip    = fmaf(m0, y0, -d);            // -mink(mean, y)
      float alpha = fmaxf(ip, 1.f + 1e-7f);
      float dist  = facosh(alpha);
      float u0    = fmaf(-alpha, m0, y0);
      // ||ur||^2 = r2 - 2*alpha*dot + alpha^2*mrr (algebraic)
      float t   = fmaf(alpha, mrr, -2.f * d);
      float s2  = fmaf(alpha, t, r2s[c]);
      float msq = s2 - u0 * u0;
      float un  = fsqrt_(fmaxf(msq, 1e-12f));
      float f   = wgt[c] * dist * frcp(un);
      wv0 = fmaf(f, u0, wv0);
#pragma unroll
      for (int j = 0; j < 4; ++j) {
        f4 diff = fma4s(-alpha, mr[j], h[c][j]);
        wvr[j]  = fma4s(f, diff, wvr[j]);
      }
    }
    float pr[2] = {0.f, 0.f};
#pragma unroll
    for (int j = 0; j < 4; ++j) {
      pr[0] += dot4(wvr[j], wvr[j]);
      pr[1] += dot4(mr[j], wvr[j]);
    }
    grp_reduce<2>(pr);

    {
      float rr2  = pr[0];
      float mwv  = pr[1];
      float nrm2 = fsqrt_(fmaf(wv0, wv0, rr2));
      float sc2  = fminf(nrm2, 2.f) * frcp(fmaxf(nrm2, 1e-12f));
      float tt   = 0.1f * sc2;                   // fold clip + 0.1 step
      float msqu = tt * tt * (rr2 - wv0 * wv0);  // mink(u,u)
      float un2  = fsqrt_(fmaxf(msqu, 1e-12f));
      float shv, chv;
      fsinhcosh(un2, shv, chv);
      float gg = shv * tt * frcp(un2);
#pragma unroll
      for (int j = 0; j < 4; ++j) mr[j] = fma4s(chv, mr[j], gg * wvr[j]);
      // ||mr'||^2 = chv^2*mrr + 2*chv*gg*(mr.wvr) + gg^2*rr2 (algebraic)
      mrr = chv * chv * mrr + 2.f * chv * gg * mwv + gg * gg * rr2;
      m0  = fsqrt_(1.f + mrr);                   // projx
    }
  }

  {
    float* o = out + 4 * HOFF + (size_t)pt * OUTS;
    if (m == 0) o[0] = m0;
#pragma unroll
    for (int j = 0; j < 4; ++j) {
      int base = 1 + 4 * m + 64 * j;
      f4 v = mr[j];
      o[base] = v.x; o[base + 1] = v.y; o[base + 2] = v.z; o[base + 3] = v.w;
    }
  }
}

}  // namespace

extern "C" void kernel_launch(void* const* d_in, const int* in_sizes, int n_in,
                              void* d_out, int out_size, void* d_ws, size_t ws_size,
                              hipStream_t stream) {
  (void)in_sizes; (void)n_in; (void)out_size; (void)d_ws; (void)ws_size;
  encode_kernel<<<K1_GRID, 256, 0, stream>>>(
      (const float*)d_in[0], (const float*)d_in[1], (const float*)d_in[2],
      (const float*)d_in[3], (const float*)d_in[4], (const float*)d_in[5],
      (const float*)d_in[6], (const float*)d_in[7], (const float*)d_in[8],
      (const float*)d_in[9], (const float*)d_in[10], (const float*)d_in[11],
      (const float*)d_in[12], (float*)d_out);
  fusion_kernel<<<K2_GRID, 256, 0, stream>>>(
      (const float*)d_in[13], (float*)d_out);
}